// Round 2
// baseline (432.300 us; speedup 1.0000x reference)
//
#include <hip/hip_runtime.h>

typedef __bf16 bf16;
typedef __bf16 bf16x8 __attribute__((ext_vector_type(8)));
typedef float floatx4 __attribute__((ext_vector_type(4)));

#define BATCH 128
#define SEQ   2048
#define HID   128
#define TWOH  256
#define CH    128
#define NCH   16
#define MTOT  (BATCH * SEQ)    // 262144

__device__ __forceinline__ float fast_tanh(float x) {
    float e = __builtin_amdgcn_exp2f(2.88539008177793f * x);
    return 1.0f - 2.0f * __builtin_amdgcn_rcpf(e + 1.0f);
}
__device__ __forceinline__ float fast_sigmoid(float x) {
    return __builtin_amdgcn_rcpf(1.0f + __builtin_amdgcn_exp2f(-1.44269504088896f * x));
}

union PK8 { uint4 u; bf16 h[8]; };
union PK4 { unsigned long long u; bf16 h[4]; };

// ---- one-time f32 -> bf16 conversion of Wx2h (both layers) ----
__global__ __launch_bounds__(256) void convert_w_k(const float* __restrict__ W,
                                                   bf16* __restrict__ Wb) {
    int i = blockIdx.x * 256 + threadIdx.x;   // 16384 float4 groups
    float4 v = ((const float4*)W)[i];
    PK4 pk;
    pk.h[0] = (bf16)v.x; pk.h[1] = (bf16)v.y;
    pk.h[2] = (bf16)v.z; pk.h[3] = (bf16)v.w;
    ((unsigned long long*)Wb)[i] = pk.u;
}

// ---- GEMM + tanh + fused per-chunk column sums ----
// block = one (b,chunk): 128 rows x 256 cols, K=128. 256 thr = 2x2 waves.
// MFMA operands swapped => D transposed: G row = lane&15, G col = quad*4+reg
// => 4 acc regs are 4 contiguous G columns => packed 8B stores.
template <bool AF32>
__global__ __launch_bounds__(256, 2) void gemm_tanh_k(const void* __restrict__ Aptr,
                                                      const bf16* __restrict__ Wb,
                                                      bf16* __restrict__ G,
                                                      float* __restrict__ P) {
    extern __shared__ char smem[];
    bf16* As = (bf16*)smem;          // [128][128], 8-elem groups XOR-swizzled by row&7
    bf16* Bs = As + 128 * 128;

    const int tid  = threadIdx.x;
    const int lane = tid & 63;
    const int wid  = tid >> 6;
    const int wr   = wid >> 1;
    const int wc   = wid & 1;
    const long rowBase = (long)blockIdx.x * 128;

    if (AF32) {
        const float4* A4 = (const float4*)((const float*)Aptr + rowBase * HID);
        #pragma unroll
        for (int it = 0; it < 16; ++it) {
            int i  = it * 256 + tid;
            int r  = i >> 5;
            int c4 = i & 31;
            float4 v = A4[i];
            int g = c4 >> 1, hf = c4 & 1;
            PK4 pk;
            pk.h[0] = (bf16)v.x; pk.h[1] = (bf16)v.y;
            pk.h[2] = (bf16)v.z; pk.h[3] = (bf16)v.w;
            *(unsigned long long*)&As[r * 128 + ((g ^ (r & 7)) << 3) + (hf << 2)] = pk.u;
        }
    } else {
        const uint4* A8 = (const uint4*)((const bf16*)Aptr + rowBase * HID);
        #pragma unroll
        for (int it = 0; it < 8; ++it) {
            int i = it * 256 + tid;
            int r = i >> 4;
            int g = i & 15;
            uint4 v = A8[i];
            *(uint4*)&As[r * 128 + ((g ^ (r & 7)) << 3)] = v;
        }
    }

    const int quad = lane >> 4;
    const int l16  = lane & 15;

    for (int half = 0; half < 2; ++half) {
        if (half) __syncthreads();   // all reads of Bs done before restage
        const uint4* W8 = (const uint4*)(Wb + half * 128 * HID);
        #pragma unroll
        for (int it = 0; it < 8; ++it) {
            int i = it * 256 + tid;
            int r = i >> 4;
            int g = i & 15;
            uint4 v = W8[i];
            *(uint4*)&Bs[r * 128 + ((g ^ (r & 7)) << 3)] = v;
        }
        __syncthreads();

        floatx4 acc[4][4];
        #pragma unroll
        for (int a = 0; a < 4; ++a)
            #pragma unroll
            for (int b2 = 0; b2 < 4; ++b2) acc[a][b2] = (floatx4){0.f, 0.f, 0.f, 0.f};

        #pragma unroll
        for (int kk = 0; kk < 128; kk += 32) {
            bf16x8 af[4], bfr[4];
            int kg = (kk >> 3) + quad;
            #pragma unroll
            for (int mi = 0; mi < 4; ++mi) {
                int r = wr * 64 + mi * 16 + l16;
                af[mi] = *(const bf16x8*)&As[r * 128 + ((kg ^ (r & 7)) << 3)];
            }
            #pragma unroll
            for (int ni = 0; ni < 4; ++ni) {
                int n = wc * 64 + ni * 16 + l16;
                bfr[ni] = *(const bf16x8*)&Bs[n * 128 + ((kg ^ (n & 7)) << 3)];
            }
            #pragma unroll
            for (int mi = 0; mi < 4; ++mi)
                #pragma unroll
                for (int ni = 0; ni < 4; ++ni)
                    acc[mi][ni] = __builtin_amdgcn_mfma_f32_16x16x32_bf16(
                        bfr[ni], af[mi], acc[mi][ni], 0, 0, 0);  // swapped => D^T
        }

        // epilogue: tanh -> bf16, packed 8B stores; accumulate column sums
        float ps[4][4];
        #pragma unroll
        for (int ni = 0; ni < 4; ++ni)
            #pragma unroll
            for (int rr = 0; rr < 4; ++rr) ps[ni][rr] = 0.f;

        #pragma unroll
        for (int mi = 0; mi < 4; ++mi) {
            int row = (int)rowBase + wr * 64 + mi * 16 + l16;
            #pragma unroll
            for (int ni = 0; ni < 4; ++ni) {
                int col = half * 128 + wc * 64 + ni * 16 + quad * 4;
                PK4 pk;
                #pragma unroll
                for (int rr = 0; rr < 4; ++rr) {
                    bf16 bv = (bf16)fast_tanh(acc[mi][ni][rr]);
                    pk.h[rr] = bv;
                    ps[ni][rr] += (float)bv;   // sum the rounded value
                }
                *(unsigned long long*)&G[(long)row * TWOH + col] = pk.u;
            }
        }
        // reduce col sums over the 16 l16-lanes (rows), then atomicAdd to P
        #pragma unroll
        for (int ni = 0; ni < 4; ++ni)
            #pragma unroll
            for (int rr = 0; rr < 4; ++rr) {
                float v = ps[ni][rr];
                #pragma unroll
                for (int m = 1; m < 16; m <<= 1) v += __shfl_xor(v, m);
                if (l16 == 0) {
                    int col = half * 128 + wc * 64 + ni * 16 + quad * 4 + rr;
                    atomicAdd(&P[((long)blockIdx.x << 8) + col], v);
                }
            }
    }
}

// in-place exclusive scan over the NCH chunks, per (b, ch)
__global__ __launch_bounds__(256) void scan_partials_k(float* __restrict__ P) {
    int ch = threadIdx.x;
    long b = blockIdx.x;
    float run = 0.f;
    for (int c = 0; c < NCH; ++c) {
        long idx = ((b * NCH + c) << 8) + ch;
        float v = P[idx];
        P[idx] = run;
        run += v;
    }
}

// h(t,j) = P2 - relu(P1)*g2, vectorized 8 ch/thread, per-(b,chunk) block.
// 256 thr = 16 t-slices x 16 ch-groups; LDS scan over slices.
__global__ __launch_bounds__(256) void compute_h_k(const bf16* __restrict__ G,
                                                   const float* __restrict__ P,
                                                   bf16* __restrict__ Hb) {
    __shared__ float sub1[16][128];
    __shared__ float sub2[16][128];
    const int tid = threadIdx.x;
    const int cg = tid & 15, ts = tid >> 4;
    const long blk = blockIdx.x;
    const long gbase = blk * CH * TWOH + cg * 8;

    float s1[8], s2[8];
    #pragma unroll
    for (int r = 0; r < 8; ++r) { s1[r] = 0.f; s2[r] = 0.f; }
    #pragma unroll
    for (int i = 0; i < 8; ++i) {
        int t = ts * 8 + i;
        PK8 a, b;
        a.u = *(const uint4*)&G[gbase + (long)t * TWOH];
        b.u = *(const uint4*)&G[gbase + (long)t * TWOH + 128];
        #pragma unroll
        for (int r = 0; r < 8; ++r) { s1[r] += (float)a.h[r]; s2[r] += (float)b.h[r]; }
    }
    #pragma unroll
    for (int r = 0; r < 8; ++r) { sub1[ts][cg * 8 + r] = s1[r]; sub2[ts][cg * 8 + r] = s2[r]; }
    __syncthreads();
    if (tid < 128) {
        float run = 0.f;
        #pragma unroll
        for (int c = 0; c < 16; ++c) { float v = sub1[c][tid]; sub1[c][tid] = run; run += v; }
    } else {
        int j = tid - 128;
        float run = 0.f;
        #pragma unroll
        for (int c = 0; c < 16; ++c) { float v = sub2[c][j]; sub2[c][j] = run; run += v; }
    }
    __syncthreads();

    float P1[8], P2[8];
    #pragma unroll
    for (int r = 0; r < 8; ++r) {
        P1[r] = P[(blk << 8) + cg * 8 + r] + sub1[ts][cg * 8 + r];
        P2[r] = P[(blk << 8) + 128 + cg * 8 + r] + sub2[ts][cg * 8 + r];
    }
    #pragma unroll
    for (int i = 0; i < 8; ++i) {
        int t = ts * 8 + i;
        PK8 a, b, hh;
        a.u = *(const uint4*)&G[gbase + (long)t * TWOH];
        b.u = *(const uint4*)&G[gbase + (long)t * TWOH + 128];
        #pragma unroll
        for (int r = 0; r < 8; ++r) {
            float g1 = (float)a.h[r], g2 = (float)b.h[r];
            P1[r] += g1; P2[r] += g2;
            hh.h[r] = (bf16)(P2[r] - fmaxf(P1[r], 0.f) * g2);
        }
        *(uint4*)&Hb[(blk * CH + t) * HID + cg * 8] = hh.u;
    }
}

// layer-1 scan + fc dot + double sigmoid + masked sq-err, fused per (b,chunk)
__global__ __launch_bounds__(256) void final_loss_k(const bf16* __restrict__ G,
                                                    const float* __restrict__ P,
                                                    const float* __restrict__ Wfc,
                                                    const int* __restrict__ xlen,
                                                    const float* __restrict__ xlab,
                                                    float* __restrict__ out) {
    __shared__ float sub1[16][128];
    __shared__ float sub2[16][128];
    __shared__ float red[4];
    const int tid = threadIdx.x;
    const int lane = tid & 63;
    const int cg = tid & 15, ts = tid >> 4;
    const long blk = blockIdx.x;
    const int b = (int)(blk >> 4), chunk = (int)(blk & 15);
    const long gbase = blk * CH * TWOH + cg * 8;

    float s1[8], s2[8];
    #pragma unroll
    for (int r = 0; r < 8; ++r) { s1[r] = 0.f; s2[r] = 0.f; }
    #pragma unroll
    for (int i = 0; i < 8; ++i) {
        int t = ts * 8 + i;
        PK8 a, bb;
        a.u = *(const uint4*)&G[gbase + (long)t * TWOH];
        bb.u = *(const uint4*)&G[gbase + (long)t * TWOH + 128];
        #pragma unroll
        for (int r = 0; r < 8; ++r) { s1[r] += (float)a.h[r]; s2[r] += (float)bb.h[r]; }
    }
    #pragma unroll
    for (int r = 0; r < 8; ++r) { sub1[ts][cg * 8 + r] = s1[r]; sub2[ts][cg * 8 + r] = s2[r]; }
    __syncthreads();
    if (tid < 128) {
        float run = 0.f;
        #pragma unroll
        for (int c = 0; c < 16; ++c) { float v = sub1[c][tid]; sub1[c][tid] = run; run += v; }
    } else {
        int j = tid - 128;
        float run = 0.f;
        #pragma unroll
        for (int c = 0; c < 16; ++c) { float v = sub2[c][j]; sub2[c][j] = run; run += v; }
    }
    __syncthreads();

    float w0[8], w1[8], P1[8], P2[8];
    #pragma unroll
    for (int r = 0; r < 8; ++r) {
        w0[r] = Wfc[2 * HID + cg * 8 + r];
        w1[r] = Wfc[3 * HID + cg * 8 + r];
        P1[r] = P[(blk << 8) + cg * 8 + r] + sub1[ts][cg * 8 + r];
        P2[r] = P[(blk << 8) + 128 + cg * 8 + r] + sub2[ts][cg * 8 + r];
    }
    const int xl = xlen[b];
    const float lab = xlab[b];
    float lsum = 0.f;
    #pragma unroll
    for (int i = 0; i < 8; ++i) {
        int t = ts * 8 + i;
        PK8 a, bb;
        a.u = *(const uint4*)&G[gbase + (long)t * TWOH];
        bb.u = *(const uint4*)&G[gbase + (long)t * TWOH + 128];
        float z0 = 0.f, z1 = 0.f;
        #pragma unroll
        for (int r = 0; r < 8; ++r) {
            float g1 = (float)a.h[r], g2 = (float)bb.h[r];
            P1[r] += g1; P2[r] += g2;
            float h = P2[r] - fmaxf(P1[r], 0.f) * g2;
            z0 += h * w0[r]; z1 += h * w1[r];
        }
        #pragma unroll
        for (int m = 1; m < 16; m <<= 1) { z0 += __shfl_xor(z0, m); z1 += __shfl_xor(z1, m); }
        if (cg == 0) {
            float o1 = fast_sigmoid(z1 - z0);
            float sg = fast_sigmoid(o1);
            int tg = chunk * CH + t;
            float d = lab - sg;
            if (tg < xl) lsum += d * d;
        }
    }
    lsum += __shfl_xor(lsum, 16);
    lsum += __shfl_xor(lsum, 32);
    if (lane == 0) red[tid >> 6] = lsum;
    __syncthreads();
    if (tid == 0) atomicAdd(out, red[0] + red[1] + red[2] + red[3]);
}

extern "C" void kernel_launch(void* const* d_in, const int* in_sizes, int n_in,
                              void* d_out, int out_size, void* d_ws, size_t ws_size,
                              hipStream_t stream) {
    const float* x    = (const float*)d_in[0];
    const int*   xlen = (const int*)d_in[1];
    const float* xlab = (const float*)d_in[2];
    const float* Wx2h = (const float*)d_in[3];  // [2,256,128] f32
    const float* Wfc  = (const float*)d_in[4];  // [2,2,128] f32
    float* out = (float*)d_out;

    char* ws = (char*)d_ws;
    bf16*  G  = (bf16*)ws;                                            // 128 MiB
    bf16*  Hb = (bf16*)(ws + (size_t)MTOT * TWOH * 2);                // 64 MiB
    float* P  = (float*)(ws + (size_t)MTOT * TWOH * 2 + (size_t)MTOT * HID * 2);  // 2 MiB
    bf16*  Wb = (bf16*)((char*)P + (size_t)BATCH * NCH * TWOH * 4);   // 128 KiB

    hipMemsetAsync(d_out, 0, sizeof(float), stream);
    hipMemsetAsync(P, 0, (size_t)BATCH * NCH * TWOH * 4, stream);
    convert_w_k<<<64, 256, 0, stream>>>(Wx2h, Wb);

    size_t smem = 2 * 128 * 128 * sizeof(bf16);
    gemm_tanh_k<true><<<MTOT / 128, 256, smem, stream>>>(x, Wb, G, P);
    scan_partials_k<<<BATCH, 256, 0, stream>>>(P);
    compute_h_k<<<MTOT / 128, 256, 0, stream>>>(G, P, Hb);

    hipMemsetAsync(P, 0, (size_t)BATCH * NCH * TWOH * 4, stream);
    gemm_tanh_k<false><<<MTOT / 128, 256, smem, stream>>>(Hb, Wb + TWOH * HID, G, P);
    scan_partials_k<<<BATCH, 256, 0, stream>>>(P);
    final_loss_k<<<MTOT / 128, 256, 0, stream>>>(G, P, Wfc, xlen, xlab, out);
}